// Round 5
// baseline (175.898 us; speedup 1.0000x reference)
//
#include <hip/hip_runtime.h>
#include <math.h>

// PyramidROIAlign: B=2, N=1000, C=256, POOL=7x7
// p3: [2,128,128,256], p4: [2,64,64,256], p5: [2,32,32,256], all fp32 NHWC.
// Output: [2,1000,7,7,256] fp32.
//
// R5: traffic reduction. R1/R2/R4 (MLP 92..336 loads in flight/CU) all
// plateau at 60-63us with FETCH ~142MB -> not latency-bound; bound by
// TCC-level traffic (scattered 1KB gathers thrash the 4MB per-XCD L2s,
// 2.5x read amplification over the ~56MB unique footprint).
// Fix: one-block counting-sort of the 2000 boxes by (batch, level, 8x8
// spatial cell), then the main kernel processes boxes in sorted order with
// an XCD-aware block swizzle so each XCD's L2 holds one spatial cluster.
// The permutation only changes processing ORDER; outputs are written at the
// original box offsets, so correctness is permutation-invariant.

#define N_PER_B 1000
#define NBOX    2000   // B*N
#define CCH     256
#define PH      7
#define PW      7
#define WAVES_PER_BLOCK 4
#define TOTAL_WAVES (NBOX * PH)           // 14000
#define GRID_MAIN   ((TOTAL_WAVES + WAVES_PER_BLOCK - 1) / WAVES_PER_BLOCK + 7) / 8 * 8  // 3504
#define NBUCKET 512                        // 2*3*8*8 = 384 used

typedef float nfloat4 __attribute__((ext_vector_type(4)));

// ---------------- sort kernel: counting sort by (batch, level, cy, cx) ----
__global__ __launch_bounds__(1024) void sort_boxes_kernel(
    const float* __restrict__ boxes, int* __restrict__ order)
{
    __shared__ int hist[NBUCKET];
    __shared__ int offs[NBUCKET];
    __shared__ int keys[NBOX];

    const int t = threadIdx.x;
    if (t < NBUCKET) hist[t] = 0;
    __syncthreads();

    for (int i = t; i < NBOX; i += 1024) {
        const float y1 = boxes[4 * i + 0];
        const float x1 = boxes[4 * i + 1];
        const float y2 = boxes[4 * i + 2];
        const float x2 = boxes[4 * i + 3];
        const float h = y2 - y1, w = x2 - x1;
        const float lvl = ceilf(5.0f + logf(h * w) / 0.69314718055994530942f);
        const int level = (int)fminf(fmaxf(lvl, 3.0f), 5.0f);
        const int b  = (i >= N_PER_B) ? 1 : 0;
        int cy = (int)((y1 + y2) * 4.0f); cy = cy < 0 ? 0 : (cy > 7 ? 7 : cy);
        int cx = (int)((x1 + x2) * 4.0f); cx = cx < 0 ? 0 : (cx > 7 ? 7 : cx);
        const int key = (((b * 3 + (level - 3)) * 8 + cy) * 8 + cx);
        keys[i] = key;
        atomicAdd(&hist[key], 1);
    }
    __syncthreads();

    // inclusive Hillis-Steele scan over NBUCKET, then make exclusive
    if (t < NBUCKET) offs[t] = hist[t];
    __syncthreads();
    for (int d = 1; d < NBUCKET; d <<= 1) {
        int v = 0;
        if (t < NBUCKET && t >= d) v = offs[t - d];
        __syncthreads();
        if (t < NBUCKET) offs[t] += v;
        __syncthreads();
    }
    if (t < NBUCKET) hist[t] = offs[t] - hist[t];   // exclusive base, reused as cursor
    __syncthreads();

    for (int i = t; i < NBOX; i += 1024) {
        const int pos = atomicAdd(&hist[keys[i]], 1);
        order[pos] = i;
    }
}

// ---------------- main kernel --------------------------------------------
__global__ __launch_bounds__(256, 3) void pyramid_roi_align_kernel(
    const float* __restrict__ boxes,   // [2000,4] y1,x1,y2,x2
    const float* __restrict__ p3,      // [2,128,128,256]
    const float* __restrict__ p4,      // [2,64,64,256]
    const float* __restrict__ p5,      // [2,32,32,256]
    const int*   __restrict__ order,   // [2000] sorted box ids (or null)
    float* __restrict__ out)           // [2000,49,256]
{
    // XCD-aware swizzle: consecutive blocks round-robin XCDs; remap so each
    // XCD gets a CONTIGUOUS range of the sorted box stream.
    const int nb_per_xcd = GRID_MAIN / 8;                 // 438
    const int vb   = (blockIdx.x & 7) * nb_per_xcd + (blockIdx.x >> 3);
    const int wave = vb * WAVES_PER_BLOCK + (threadIdx.x >> 6);
    if (wave >= TOTAL_WAVES) return;
    const int lane = threadIdx.x & 63;
    const int c    = lane * 4;

    const int sidx = wave / PH;
    const int iy   = wave - sidx * PH;
    const int box  = order ? order[sidx] : sidx;

    // ---- per-box setup (wave-uniform) ----
    const float y1 = boxes[box * 4 + 0];
    const float x1 = boxes[box * 4 + 1];
    const float y2 = boxes[box * 4 + 2];
    const float x2 = boxes[box * 4 + 3];
    const float h  = y2 - y1;
    const float w  = x2 - x1;

    // roi_level = clip(ceil(5 + log(h*w)/log(2)), 3, 5) -- match ref op order
    const float lvl  = ceilf(5.0f + logf(h * w) / 0.69314718055994530942f);
    const float lvlc = fminf(fmaxf(lvl, 3.0f), 5.0f);
    const int level  = (int)lvlc;

    const float* feat;
    int H;
    if (level <= 3)      { feat = p3; H = 128; }
    else if (level == 4) { feat = p4; H = 64;  }
    else                 { feat = p5; H = 32;  }
    const int W = H;

    const int b = (box >= N_PER_B) ? 1 : 0;
    feat += (size_t)b * H * W * CCH;

    const float Hm1 = (float)(H - 1);
    const float Wm1 = (float)(W - 1);

    // ys = y1*(H-1) + iy * ((y2-y1)*(H-1)/6)   (match reference exactly)
    const float ys = y1 * Hm1 + (float)iy * (h * Hm1 / 6.0f);
    const bool  vy = (ys >= 0.0f) && (ys <= Hm1);

    const float y0f  = floorf(ys);
    const float wy   = ys - y0f;
    const float omwy = 1.0f - wy;

    const int y0i = (int)fminf(fmaxf(y0f,        0.0f), Hm1);
    const int y1i = (int)fminf(fmaxf(y0f + 1.0f, 0.0f), Hm1);

    const float* row0 = feat + (size_t)y0i * W * CCH + c;
    const float* row1 = feat + (size_t)y1i * W * CCH + c;

    const float xstep = w * Wm1 / 6.0f;

    // ---- phase 1: issue all 28 loads ----
    nfloat4 v00[PW], v01[PW], v10[PW], v11[PW];
    float   wxv[PW];
    bool    vxv[PW];

#pragma unroll
    for (int ix = 0; ix < PW; ++ix) {
        const float xs = x1 * Wm1 + (float)ix * xstep;
        vxv[ix] = (xs >= 0.0f) && (xs <= Wm1);
        const float x0f = floorf(xs);
        wxv[ix] = xs - x0f;
        const int x0i = (int)fminf(fmaxf(x0f,        0.0f), Wm1);
        const int x1i = (int)fminf(fmaxf(x0f + 1.0f, 0.0f), Wm1);
        v00[ix] = *(const nfloat4*)(row0 + (size_t)x0i * CCH);
        v01[ix] = *(const nfloat4*)(row0 + (size_t)x1i * CCH);
        v10[ix] = *(const nfloat4*)(row1 + (size_t)x0i * CCH);
        v11[ix] = *(const nfloat4*)(row1 + (size_t)x1i * CCH);
    }

    // ---- phase 2: lerp + nontemporal store (original box offset!) ----
    float* dst_base = out + ((size_t)box * (PH * PW) + (size_t)iy * PW) * CCH + c;

#pragma unroll
    for (int ix = 0; ix < PW; ++ix) {
        const float wx   = wxv[ix];
        const float omwx = 1.0f - wx;

        nfloat4 res = (v00[ix] * omwx + v01[ix] * wx) * omwy
                    + (v10[ix] * omwx + v11[ix] * wx) * wy;

        if (!(vy && vxv[ix])) res = (nfloat4)0.0f;

        __builtin_nontemporal_store(res, (nfloat4*)(dst_base + (size_t)ix * CCH));
    }
}

extern "C" void kernel_launch(void* const* d_in, const int* in_sizes, int n_in,
                              void* d_out, int out_size, void* d_ws, size_t ws_size,
                              hipStream_t stream) {
    const float* boxes = (const float*)d_in[0];
    // d_in[1] = positive_indices (unused by reference)
    const float* p3 = (const float*)d_in[2];
    const float* p4 = (const float*)d_in[3];
    const float* p5 = (const float*)d_in[4];
    // d_in[5] = config (unused)
    float* out = (float*)d_out;

    int* order = nullptr;
    if (ws_size >= NBOX * sizeof(int)) {
        order = (int*)d_ws;
        hipLaunchKernelGGL(sort_boxes_kernel, dim3(1), dim3(1024), 0, stream,
                           boxes, order);
    }

    hipLaunchKernelGGL(pyramid_roi_align_kernel, dim3(GRID_MAIN), dim3(256), 0, stream,
                       boxes, p3, p4, p5, order, out);
}